// Round 11
// baseline (251.930 us; speedup 1.0000x reference)
//
#include <hip/hip_runtime.h>
#include <hip/hip_fp16.h>

// GCN 2-layer GraphConv (norm='both'), fp32 in/out, fp16 intermediates.
// Round 17: instruction-diet + ILP on the proven r16 structure.
//   - pull64/pull32 gather: ILP-4 (4 col + 4 uint4 loads in flight per
//     lane group, 2 acc sets) vs r16's 2.
//   - pull64 phase2: W2 column held in 64 VGPRs (static unroll), xrow read
//     as broadcast float4 -> LDS issues 512 -> 64 per wave.
//   - xw1: W1 column in 64 VGPRs (global, L1-resident), xs broadcast float4
//     -> LDS issues halved.
//   kB_scatter / kC_build byte-identical to r16.
//
// ws: int deg[N] | rowptr[N] | f32 in_norm[N] | out_norm[N] | int gcur[1024] |
//     int col[E] | f16 h1[64N] | f16 h2[32N]
//     binbuf_d[391*CAP ints] aliases h2+ (dead before pull64 writes h2);
//     binbuf_s[391*CAP bytes] follows.

#define BIN_SH 8
#define NBINS 391             // ceil(100000/256)
#define SRC_OFF 512
#define CAP 5120              // mean 4096 + 16 sigma
#define KB_EPT 8              // 8192 edges per 1024-thread kB block

// ---- kB_scatter: LDS-staged multisplit, 1024 threads (r14 proven) ----
__global__ __launch_bounds__(1024) void kB_scatter(
    const int* __restrict__ src, const int* __restrict__ dst,
    int* __restrict__ gcur, int* __restrict__ binbuf_d,
    unsigned char* __restrict__ binbuf_s, int E) {
  __shared__ __align__(16) char smem[53248];
  int* stage_d = (int*)smem;                         // 8192 ints (32 KB)
  unsigned char* stage_s = (unsigned char*)(smem + 32768);  // 8192 B
  int* cnt_d  = (int*)(smem + 40960);                // 512
  int* cnt_s  = (int*)(smem + 43008);                // 512
  int* scan_d = (int*)(smem + 45056);                // 512
  int* scan_s = (int*)(smem + 47104);                // 512
  int* base_d = (int*)(smem + 49152);                // 512
  int* base_s = (int*)(smem + 51200);                // 512
  int t = threadIdx.x;

  if (t < 512) { cnt_d[t] = 0; cnt_s[t] = 0; }
  __syncthreads();
  int base = blockIdx.x * (1024 * KB_EPT);
  // pass 1: count
#pragma unroll
  for (int i = 0; i < KB_EPT; i++) {
    int e = base + i * 1024 + t;
    if (e < E) {
      atomicAdd(&cnt_d[dst[e] >> BIN_SH], 1);
      atomicAdd(&cnt_s[src[e] >> BIN_SH], 1);
    }
  }
  __syncthreads();
  // pass 2: two independent 512-entry scans via masked HS over 1024 threads
  {
    int* tmp = stage_d;
    int v = (t < 512) ? cnt_d[t] : cnt_s[t - 512];
    tmp[t] = v;
    __syncthreads();
#pragma unroll
    for (int off = 1; off < 512; off <<= 1) {
      int val = ((t & 511) >= off) ? tmp[t - off] : 0;
      __syncthreads();
      tmp[t] += val;
      __syncthreads();
    }
    int ex = tmp[t] - v;
    if (t < 512) scan_d[t] = ex; else scan_s[t - 512] = ex;
    __syncthreads();
  }
  // pass 2b: reserve global segments; then reset cnt as place cursors
  if (t < 512) {
    int c = cnt_d[t];
    base_d[t] = c ? atomicAdd(&gcur[t], c) : 0;
  } else {
    int i = t - 512;
    int cs = cnt_s[i];
    base_s[i] = cs ? atomicAdd(&gcur[SRC_OFF + i], cs) : 0;
  }
  __syncthreads();
  if (t < 512) { cnt_d[t] = 0; cnt_s[t] = 0; }
  __syncthreads();
  // pass 3: scatter into LDS staging (re-read src/dst, L2-hot)
#pragma unroll
  for (int i = 0; i < KB_EPT; i++) {
    int e = base + i * 1024 + t;
    if (e < E) {
      int d = dst[e], s = src[e];
      int bd = d >> BIN_SH;
      int rd = atomicAdd(&cnt_d[bd], 1);
      stage_d[scan_d[bd] + rd] = ((d & 255) << 17) | s;
      int bs = s >> BIN_SH;
      int rs = atomicAdd(&cnt_s[bs], 1);
      stage_s[scan_s[bs] + rs] = (unsigned char)(s & 255);
    }
  }
  __syncthreads();
  // pass 4: coalesced per-bin segment copy to global (16 waves)
  int wv = t >> 6, ln = t & 63;
  for (int b = wv; b < NBINS; b += 16) {
    int sd = scan_d[b], cd = scan_d[b + 1] - sd;
    int gd = b * CAP + base_d[b];
    for (int j = ln; j < cd; j += 64) binbuf_d[gd + j] = stage_d[sd + j];
    int ss = scan_s[b], cs = scan_s[b + 1] - ss;
    int gs = b * CAP + base_s[b];
    for (int j = ln; j < cs; j += 64) binbuf_s[gs + j] = stage_s[ss + j];
  }
}

// ---- xw1: h1 = x @ W1; W1 column in 64 VGPRs, xs broadcast float4 ----
__global__ __launch_bounds__(256) void xw1(
    const float* __restrict__ x, const float* __restrict__ W,
    __half* __restrict__ h1, int n) {
  __shared__ float xs[16 * 64];   // 4 KB
  int t = threadIdx.x;
  int c = t & 63, rq = t >> 6;
  float wr[64];
#pragma unroll
  for (int k = 0; k < 64; k++) wr[k] = W[k * 64 + c];   // L1-resident 16KB
  int row0 = blockIdx.x * 16;
  {
    int r = t >> 4, k4 = t & 15;
    int row = row0 + r;
    float4 v = make_float4(0.f, 0.f, 0.f, 0.f);
    if (row < n) v = ((const float4*)x)[(size_t)row * 16 + k4];
    ((float4*)xs)[t] = v;
  }
  __syncthreads();
  float acc[4] = {0.f, 0.f, 0.f, 0.f};
#pragma unroll
  for (int kq = 0; kq < 16; kq++) {
#pragma unroll
    for (int rr = 0; rr < 4; rr++) {
      const float4 xv = *(const float4*)&xs[(rq + rr * 4) * 64 + kq * 4];
      acc[rr] += xv.x * wr[4 * kq] + xv.y * wr[4 * kq + 1] +
                 xv.z * wr[4 * kq + 2] + xv.w * wr[4 * kq + 3];
    }
  }
#pragma unroll
  for (int rr = 0; rr < 4; rr++) {
    int row = row0 + rq + rr * 4;
    if (row < n) h1[(size_t)row * 64 + c] = __float2half(acc[rr]);
  }
}

// ---- kC: [0,NBINS) dst CSR build; [NBINS,2*NBINS) src count -> out_norm,
//          then prescale h1 rows by out_norm (in place, coalesced) ----
__global__ __launch_bounds__(256) void kC_build(
    const int* __restrict__ gcur, const int* __restrict__ binbuf_d,
    const unsigned char* __restrict__ binbuf_s,
    int* __restrict__ col, int* __restrict__ rowptr, int* __restrict__ deg,
    float* __restrict__ in_norm, float* __restrict__ out_norm,
    __half* __restrict__ h1, int n) {
  __shared__ int lcnt[256];
  __shared__ int lptr[256];
  __shared__ int red[256];
  int b = blockIdx.x;
  int t = threadIdx.x;
  if (b >= NBINS) {
    // src-bin byte count -> out_norm, then scale h1 rows of this bin
    int sb = b - NBINS;
    int cnt = gcur[SRC_OFF + sb];
    const unsigned int* p4 =
        (const unsigned int*)(binbuf_s + (size_t)sb * CAP);
    lcnt[t] = 0;
    __syncthreads();
    int cw = (cnt + 3) >> 2;
    for (int i = t; i < cw; i += 256) {
      unsigned int v = p4[i];
      int rem = cnt - i * 4;
      atomicAdd(&lcnt[v & 255], 1);
      if (rem > 1) atomicAdd(&lcnt[(v >> 8) & 255], 1);
      if (rem > 2) atomicAdd(&lcnt[(v >> 16) & 255], 1);
      if (rem > 3) atomicAdd(&lcnt[v >> 24], 1);
    }
    __syncthreads();
    int node0 = sb << BIN_SH;
    int node = node0 + t;
    float o = rsqrtf(fmaxf((float)lcnt[t], 1.0f));
    if (node < n) out_norm[node] = o;
    float* onn = (float*)lptr;
    onn[t] = o;
    __syncthreads();
    uint4* h1q = (uint4*)h1 + (size_t)node0 * 8;
#pragma unroll
    for (int i = 0; i < 8; i++) {
      int idx = i * 256 + t;
      int r = idx >> 3;
      if (node0 + r < n) {
        float sc = onn[r];
        uint4 v = h1q[idx];
        __half2* hp = (__half2*)&v;
#pragma unroll
        for (int q = 0; q < 4; q++) {
          float2 f = __half22float2(hp[q]);
          f.x *= sc; f.y *= sc;
          hp[q] = __float22half2_rn(f);
        }
        h1q[idx] = v;
      }
    }
    return;
  }
  // compact col base = sum of dst-bin counts before b
  int part = 0;
  if (t < b) part = gcur[t];
  if (t + 256 < b) part += gcur[t + 256];
  red[t] = part;
  __syncthreads();
#pragma unroll
  for (int off = 128; off > 0; off >>= 1) {
    if (t < off) red[t] += red[t + off];
    __syncthreads();
  }
  int ebase = red[0];
  int cnt = gcur[b];
  const int* items = binbuf_d + (size_t)b * CAP;
  lcnt[t] = 0;
  __syncthreads();
  for (int i = t; i < cnt; i += 256) atomicAdd(&lcnt[items[i] >> 17], 1);
  __syncthreads();
  int cv = lcnt[t];
  lptr[t] = cv;
  __syncthreads();
#pragma unroll
  for (int off = 1; off < 256; off <<= 1) {
    int val = (t >= off) ? lptr[t - off] : 0;
    __syncthreads();
    lptr[t] += val;
    __syncthreads();
  }
  int ex = lptr[t] - cv;
  int node = (b << BIN_SH) + t;
  if (node < n) {
    rowptr[node] = ebase + ex;
    deg[node] = cv;
    in_norm[node] = rsqrtf(fmaxf((float)cv, 1.0f));
  }
  __syncthreads();
  lptr[t] = ex;
  __syncthreads();
  for (int i = t; i < cnt; i += 256) {
    int v = items[i];
    int r = atomicAdd(&lptr[v >> 17], 1);
    col[ebase + r] = v & 0x1FFFF;   // block-local region -> L2 merges
  }
}

__device__ inline void add8h(float* a, uint4 r) {
  const __half2* hp = reinterpret_cast<const __half2*>(&r);
#pragma unroll
  for (int i = 0; i < 4; i++) {
    float2 f = __half22float2(hp[i]);
    a[2 * i] += f.x;
    a[2 * i + 1] += f.y;
  }
}

// ---- pull64 + fused xw2: wave = 8 nodes x 8 lanes; ILP-4 gather;
//      phase2 with W2 column in VGPRs ----
__global__ __launch_bounds__(256) void pull64_xw2(
    const int* __restrict__ rowptr, const int* __restrict__ deg,
    const int* __restrict__ col, const __half* __restrict__ h1,
    const float* __restrict__ out_norm, const float* __restrict__ in_norm,
    const float* __restrict__ b1, const float* __restrict__ W2,
    __half* __restrict__ h2, int n) {
  __shared__ float xrow[32][64];   // 8 KB
  int t = threadIdx.x;
  int w = t >> 6, l = t & 63, g = l >> 3, fq = l & 7;
  int r = w * 8 + g;                 // row in block (0..31)
  int node = blockIdx.x * 32 + r;

  if (node < n) {
    int beg = rowptr[node];
    int dg = deg[node];
    float a0[8] = {0, 0, 0, 0, 0, 0, 0, 0};
    float a1[8] = {0, 0, 0, 0, 0, 0, 0, 0};
    int i = 0;
    for (; i + 4 <= dg; i += 4) {
      int s0 = col[beg + i];
      int s1 = col[beg + i + 1];
      int s2 = col[beg + i + 2];
      int s3 = col[beg + i + 3];
      uint4 v0 = ((const uint4*)h1)[(size_t)s0 * 8 + fq];
      uint4 v1 = ((const uint4*)h1)[(size_t)s1 * 8 + fq];
      uint4 v2 = ((const uint4*)h1)[(size_t)s2 * 8 + fq];
      uint4 v3 = ((const uint4*)h1)[(size_t)s3 * 8 + fq];
      add8h(a0, v0);
      add8h(a1, v1);
      add8h(a0, v2);
      add8h(a1, v3);
    }
    for (; i < dg; i++) {
      int s = col[beg + i];
      uint4 v = ((const uint4*)h1)[(size_t)s * 8 + fq];
      add8h(a0, v);
    }
    float innv = in_norm[node];
    float onnv = out_norm[node];
    float4 ba = ((const float4*)b1)[fq * 2];
    float4 bb = ((const float4*)b1)[fq * 2 + 1];
    float4 o0, o1;
    o0.x = fmaxf((a0[0] + a1[0]) * innv + ba.x, 0.0f) * onnv;
    o0.y = fmaxf((a0[1] + a1[1]) * innv + ba.y, 0.0f) * onnv;
    o0.z = fmaxf((a0[2] + a1[2]) * innv + ba.z, 0.0f) * onnv;
    o0.w = fmaxf((a0[3] + a1[3]) * innv + ba.w, 0.0f) * onnv;
    o1.x = fmaxf((a0[4] + a1[4]) * innv + bb.x, 0.0f) * onnv;
    o1.y = fmaxf((a0[5] + a1[5]) * innv + bb.y, 0.0f) * onnv;
    o1.z = fmaxf((a0[6] + a1[6]) * innv + bb.z, 0.0f) * onnv;
    o1.w = fmaxf((a0[7] + a1[7]) * innv + bb.w, 0.0f) * onnv;
    *(float4*)&xrow[r][fq * 8] = o0;
    *(float4*)&xrow[r][fq * 8 + 4] = o1;
  }
  __syncthreads();
  // phase 2: h2[node][c] = xrow @ W2; W2 column in 64 VGPRs (static unroll)
  int c = t & 31, nq = t >> 5;
  float w2r[64];
#pragma unroll
  for (int k = 0; k < 64; k++) w2r[k] = W2[k * 32 + c];   // L1-resident 8KB
#pragma unroll
  for (int p = 0; p < 4; p++) {
    int rr = p * 8 + nq;
    int nd = blockIdx.x * 32 + rr;
    if (nd < n) {
      const float* row = xrow[rr];
      float dot = 0.f;
#pragma unroll
      for (int kq = 0; kq < 16; kq++) {
        const float4 xv = *(const float4*)&row[kq * 4];   // broadcast b128
        dot += xv.x * w2r[4 * kq] + xv.y * w2r[4 * kq + 1] +
               xv.z * w2r[4 * kq + 2] + xv.w * w2r[4 * kq + 3];
      }
      h2[(size_t)nd * 32 + c] = __float2half(dot);
    }
  }
}

// ---- pull 32 feats + epilogue: wave = 16 nodes x 4 lanes; ILP-4 ----
__global__ __launch_bounds__(256) void gcn_pull32(const int* __restrict__ rowptr,
                                                  const int* __restrict__ deg,
                                                  const int* __restrict__ col,
                                                  const __half* __restrict__ h,
                                                  const float* __restrict__ in_norm,
                                                  const float* __restrict__ b2,
                                                  float* __restrict__ out, int n) {
  int t = threadIdx.x;
  int w = t >> 6, l = t & 63, g = l >> 2, fq = l & 3;
  int node = blockIdx.x * 64 + w * 16 + g;
  if (node >= n) return;
  int beg = rowptr[node];
  int dg = deg[node];
  float a0[8] = {0, 0, 0, 0, 0, 0, 0, 0};
  float a1[8] = {0, 0, 0, 0, 0, 0, 0, 0};
  int i = 0;
  for (; i + 4 <= dg; i += 4) {
    int s0 = col[beg + i];
    int s1 = col[beg + i + 1];
    int s2 = col[beg + i + 2];
    int s3 = col[beg + i + 3];
    uint4 v0 = ((const uint4*)h)[(size_t)s0 * 4 + fq];
    uint4 v1 = ((const uint4*)h)[(size_t)s1 * 4 + fq];
    uint4 v2 = ((const uint4*)h)[(size_t)s2 * 4 + fq];
    uint4 v3 = ((const uint4*)h)[(size_t)s3 * 4 + fq];
    add8h(a0, v0);
    add8h(a1, v1);
    add8h(a0, v2);
    add8h(a1, v3);
  }
  for (; i < dg; i++) {
    int s = col[beg + i];
    uint4 v = ((const uint4*)h)[(size_t)s * 4 + fq];
    add8h(a0, v);
  }
  float innv = in_norm[node];
  float4 b2a = ((const float4*)b2)[fq * 2];
  float4 b2b = ((const float4*)b2)[fq * 2 + 1];
  float4 o0, o1;
  o0.x = (a0[0] + a1[0]) * innv + b2a.x;
  o0.y = (a0[1] + a1[1]) * innv + b2a.y;
  o0.z = (a0[2] + a1[2]) * innv + b2a.z;
  o0.w = (a0[3] + a1[3]) * innv + b2a.w;
  o1.x = (a0[4] + a1[4]) * innv + b2b.x;
  o1.y = (a0[5] + a1[5]) * innv + b2b.y;
  o1.z = (a0[6] + a1[6]) * innv + b2b.z;
  o1.w = (a0[7] + a1[7]) * innv + b2b.w;
  ((float4*)out)[(size_t)node * 8 + fq * 2] = o0;
  ((float4*)out)[(size_t)node * 8 + fq * 2 + 1] = o1;
}

extern "C" void kernel_launch(void* const* d_in, const int* in_sizes, int n_in,
                              void* d_out, int out_size, void* d_ws, size_t ws_size,
                              hipStream_t stream) {
  const float* x   = (const float*)d_in[0];
  const int*   src = (const int*)d_in[1];
  const int*   dst = (const int*)d_in[2];
  const float* W1  = (const float*)d_in[3];
  const float* b1  = (const float*)d_in[4];
  const float* W2  = (const float*)d_in[5];
  const float* b2  = (const float*)d_in[6];
  float* out = (float*)d_out;

  const int N = in_sizes[0] / 64;   // 100000
  const int E = in_sizes[1];        // 1600000

  int* deg        = (int*)d_ws;                // N
  int* rowptr     = deg + N;                   // N
  float* in_norm  = (float*)(rowptr + N);      // N
  float* out_norm = in_norm + N;               // N
  int* gcur       = (int*)(out_norm + N);      // 1024
  int* col        = gcur + 1024;               // E (compact)
  __half* h1 = (__half*)(col + E);             // 64N halves
  __half* h2 = h1 + (size_t)64 * N;            // 32N halves
  int* binbuf_d = (int*)h2;                    // 391*CAP ints (aliases h2+, dead later)
  unsigned char* binbuf_s =
      (unsigned char*)(binbuf_d + (size_t)NBINS * CAP);  // 391*CAP bytes

  hipMemsetAsync(gcur, 0, 1024 * sizeof(int), stream);

  const int NKB = (E + 1024 * KB_EPT - 1) / (1024 * KB_EPT);  // 196
  const int GX = (N + 15) / 16;                               // 6250
  kB_scatter<<<NKB, 1024, 0, stream>>>(src, dst, gcur, binbuf_d, binbuf_s, E);
  xw1<<<GX, 256, 0, stream>>>(x, W1, h1, N);
  kC_build<<<2 * NBINS, 256, 0, stream>>>(gcur, binbuf_d, binbuf_s, col, rowptr,
                                          deg, in_norm, out_norm, h1, N);
  pull64_xw2<<<(N + 31) / 32, 256, 0, stream>>>(rowptr, deg, col, h1, out_norm,
                                                in_norm, b1, W2, h2, N);
  gcn_pull32<<<(N + 63) / 64, 256, 0, stream>>>(rowptr, deg, col, h2, in_norm,
                                                b2, out, N);
}

// Round 12
// 216.806 us; speedup vs baseline: 1.1620x; 1.1620x over previous
//
#include <hip/hip_runtime.h>
#include <hip/hip_fp16.h>

// GCN 2-layer GraphConv (norm='both'), fp32 in/out, fp16 intermediates.
// Round 18: REVERT r17's xw1 (W1-in-VGPR: 140 VGPR -> 10% occ -> 68us) and
//   pull64 phase2 (W2-in-VGPR, unproven) to the r16 proven forms.
//   KEEP exactly one r17 change: ILP-4 gather in pull64/pull32 (4 loads in
//   flight per lane group; costs ~16 VGPR on a 24-VGPR kernel, no occ loss).
//   kB_scatter / kC_build byte-identical to r16.
//
// ws: int deg[N] | rowptr[N] | f32 in_norm[N] | out_norm[N] | int gcur[1024] |
//     int col[E] | f16 h1[64N] | f16 h2[32N]
//     binbuf_d[391*CAP ints] aliases h2+ (dead before pull64 writes h2);
//     binbuf_s[391*CAP bytes] follows.

#define BIN_SH 8
#define NBINS 391             // ceil(100000/256)
#define SRC_OFF 512
#define CAP 5120              // mean 4096 + 16 sigma
#define KB_EPT 8              // 8192 edges per 1024-thread kB block

// ---- kB_scatter: LDS-staged multisplit, 1024 threads (r14 proven) ----
__global__ __launch_bounds__(1024) void kB_scatter(
    const int* __restrict__ src, const int* __restrict__ dst,
    int* __restrict__ gcur, int* __restrict__ binbuf_d,
    unsigned char* __restrict__ binbuf_s, int E) {
  __shared__ __align__(16) char smem[53248];
  int* stage_d = (int*)smem;                         // 8192 ints (32 KB)
  unsigned char* stage_s = (unsigned char*)(smem + 32768);  // 8192 B
  int* cnt_d  = (int*)(smem + 40960);                // 512
  int* cnt_s  = (int*)(smem + 43008);                // 512
  int* scan_d = (int*)(smem + 45056);                // 512
  int* scan_s = (int*)(smem + 47104);                // 512
  int* base_d = (int*)(smem + 49152);                // 512
  int* base_s = (int*)(smem + 51200);                // 512
  int t = threadIdx.x;

  if (t < 512) { cnt_d[t] = 0; cnt_s[t] = 0; }
  __syncthreads();
  int base = blockIdx.x * (1024 * KB_EPT);
  // pass 1: count
#pragma unroll
  for (int i = 0; i < KB_EPT; i++) {
    int e = base + i * 1024 + t;
    if (e < E) {
      atomicAdd(&cnt_d[dst[e] >> BIN_SH], 1);
      atomicAdd(&cnt_s[src[e] >> BIN_SH], 1);
    }
  }
  __syncthreads();
  // pass 2: two independent 512-entry scans via masked HS over 1024 threads
  {
    int* tmp = stage_d;
    int v = (t < 512) ? cnt_d[t] : cnt_s[t - 512];
    tmp[t] = v;
    __syncthreads();
#pragma unroll
    for (int off = 1; off < 512; off <<= 1) {
      int val = ((t & 511) >= off) ? tmp[t - off] : 0;
      __syncthreads();
      tmp[t] += val;
      __syncthreads();
    }
    int ex = tmp[t] - v;
    if (t < 512) scan_d[t] = ex; else scan_s[t - 512] = ex;
    __syncthreads();
  }
  // pass 2b: reserve global segments; then reset cnt as place cursors
  if (t < 512) {
    int c = cnt_d[t];
    base_d[t] = c ? atomicAdd(&gcur[t], c) : 0;
  } else {
    int i = t - 512;
    int cs = cnt_s[i];
    base_s[i] = cs ? atomicAdd(&gcur[SRC_OFF + i], cs) : 0;
  }
  __syncthreads();
  if (t < 512) { cnt_d[t] = 0; cnt_s[t] = 0; }
  __syncthreads();
  // pass 3: scatter into LDS staging (re-read src/dst, L2-hot)
#pragma unroll
  for (int i = 0; i < KB_EPT; i++) {
    int e = base + i * 1024 + t;
    if (e < E) {
      int d = dst[e], s = src[e];
      int bd = d >> BIN_SH;
      int rd = atomicAdd(&cnt_d[bd], 1);
      stage_d[scan_d[bd] + rd] = ((d & 255) << 17) | s;
      int bs = s >> BIN_SH;
      int rs = atomicAdd(&cnt_s[bs], 1);
      stage_s[scan_s[bs] + rs] = (unsigned char)(s & 255);
    }
  }
  __syncthreads();
  // pass 4: coalesced per-bin segment copy to global (16 waves)
  int wv = t >> 6, ln = t & 63;
  for (int b = wv; b < NBINS; b += 16) {
    int sd = scan_d[b], cd = scan_d[b + 1] - sd;
    int gd = b * CAP + base_d[b];
    for (int j = ln; j < cd; j += 64) binbuf_d[gd + j] = stage_d[sd + j];
    int ss = scan_s[b], cs = scan_s[b + 1] - ss;
    int gs = b * CAP + base_s[b];
    for (int j = ln; j < cs; j += 64) binbuf_s[gs + j] = stage_s[ss + j];
  }
}

// ---- xw1: h1 = x @ W1, 16 rows/block, broadcast-float4 inner loop (r16) ----
__global__ __launch_bounds__(256) void xw1(
    const float* __restrict__ x, const float* __restrict__ W,
    __half* __restrict__ h1, int n) {
  __shared__ float Ws[64 * 64];   // 16 KB
  __shared__ float xs[16 * 64];   // 4 KB
  int t = threadIdx.x;
#pragma unroll
  for (int i = 0; i < 16; i++) Ws[i * 256 + t] = W[i * 256 + t];
  int row0 = blockIdx.x * 16;
  {
    int r = t >> 4, k4 = t & 15;
    int row = row0 + r;
    float4 v = make_float4(0.f, 0.f, 0.f, 0.f);
    if (row < n) v = ((const float4*)x)[(size_t)row * 16 + k4];
    ((float4*)xs)[t] = v;
  }
  __syncthreads();
  int c = t & 63, rq = t >> 6;
  float acc[4] = {0.f, 0.f, 0.f, 0.f};
#pragma unroll 4
  for (int kq = 0; kq < 16; kq++) {
    float w0 = Ws[(4 * kq + 0) * 64 + c];
    float w1 = Ws[(4 * kq + 1) * 64 + c];
    float w2 = Ws[(4 * kq + 2) * 64 + c];
    float w3 = Ws[(4 * kq + 3) * 64 + c];
#pragma unroll
    for (int rr = 0; rr < 4; rr++) {
      const float4 xv = *(const float4*)&xs[(rq + rr * 4) * 64 + kq * 4];
      acc[rr] += xv.x * w0 + xv.y * w1 + xv.z * w2 + xv.w * w3;
    }
  }
#pragma unroll
  for (int rr = 0; rr < 4; rr++) {
    int row = row0 + rq + rr * 4;
    if (row < n) h1[(size_t)row * 64 + c] = __float2half(acc[rr]);
  }
}

// ---- kC: [0,NBINS) dst CSR build; [NBINS,2*NBINS) src count -> out_norm,
//          then prescale h1 rows by out_norm (in place, coalesced) ----
__global__ __launch_bounds__(256) void kC_build(
    const int* __restrict__ gcur, const int* __restrict__ binbuf_d,
    const unsigned char* __restrict__ binbuf_s,
    int* __restrict__ col, int* __restrict__ rowptr, int* __restrict__ deg,
    float* __restrict__ in_norm, float* __restrict__ out_norm,
    __half* __restrict__ h1, int n) {
  __shared__ int lcnt[256];
  __shared__ int lptr[256];
  __shared__ int red[256];
  int b = blockIdx.x;
  int t = threadIdx.x;
  if (b >= NBINS) {
    // src-bin byte count -> out_norm, then scale h1 rows of this bin
    int sb = b - NBINS;
    int cnt = gcur[SRC_OFF + sb];
    const unsigned int* p4 =
        (const unsigned int*)(binbuf_s + (size_t)sb * CAP);
    lcnt[t] = 0;
    __syncthreads();
    int cw = (cnt + 3) >> 2;
    for (int i = t; i < cw; i += 256) {
      unsigned int v = p4[i];
      int rem = cnt - i * 4;
      atomicAdd(&lcnt[v & 255], 1);
      if (rem > 1) atomicAdd(&lcnt[(v >> 8) & 255], 1);
      if (rem > 2) atomicAdd(&lcnt[(v >> 16) & 255], 1);
      if (rem > 3) atomicAdd(&lcnt[v >> 24], 1);
    }
    __syncthreads();
    int node0 = sb << BIN_SH;
    int node = node0 + t;
    float o = rsqrtf(fmaxf((float)lcnt[t], 1.0f));
    if (node < n) out_norm[node] = o;
    float* onn = (float*)lptr;
    onn[t] = o;
    __syncthreads();
    uint4* h1q = (uint4*)h1 + (size_t)node0 * 8;
#pragma unroll
    for (int i = 0; i < 8; i++) {
      int idx = i * 256 + t;
      int r = idx >> 3;
      if (node0 + r < n) {
        float sc = onn[r];
        uint4 v = h1q[idx];
        __half2* hp = (__half2*)&v;
#pragma unroll
        for (int q = 0; q < 4; q++) {
          float2 f = __half22float2(hp[q]);
          f.x *= sc; f.y *= sc;
          hp[q] = __float22half2_rn(f);
        }
        h1q[idx] = v;
      }
    }
    return;
  }
  // compact col base = sum of dst-bin counts before b
  int part = 0;
  if (t < b) part = gcur[t];
  if (t + 256 < b) part += gcur[t + 256];
  red[t] = part;
  __syncthreads();
#pragma unroll
  for (int off = 128; off > 0; off >>= 1) {
    if (t < off) red[t] += red[t + off];
    __syncthreads();
  }
  int ebase = red[0];
  int cnt = gcur[b];
  const int* items = binbuf_d + (size_t)b * CAP;
  lcnt[t] = 0;
  __syncthreads();
  for (int i = t; i < cnt; i += 256) atomicAdd(&lcnt[items[i] >> 17], 1);
  __syncthreads();
  int cv = lcnt[t];
  lptr[t] = cv;
  __syncthreads();
#pragma unroll
  for (int off = 1; off < 256; off <<= 1) {
    int val = (t >= off) ? lptr[t - off] : 0;
    __syncthreads();
    lptr[t] += val;
    __syncthreads();
  }
  int ex = lptr[t] - cv;
  int node = (b << BIN_SH) + t;
  if (node < n) {
    rowptr[node] = ebase + ex;
    deg[node] = cv;
    in_norm[node] = rsqrtf(fmaxf((float)cv, 1.0f));
  }
  __syncthreads();
  lptr[t] = ex;
  __syncthreads();
  for (int i = t; i < cnt; i += 256) {
    int v = items[i];
    int r = atomicAdd(&lptr[v >> 17], 1);
    col[ebase + r] = v & 0x1FFFF;   // block-local region -> L2 merges
  }
}

__device__ inline void add8h(float* a, uint4 r) {
  const __half2* hp = reinterpret_cast<const __half2*>(&r);
#pragma unroll
  for (int i = 0; i < 4; i++) {
    float2 f = __half22float2(hp[i]);
    a[2 * i] += f.x;
    a[2 * i + 1] += f.y;
  }
}

// ---- pull64 + fused xw2: wave = 8 nodes x 8 lanes; ILP-4 gather;
//      phase2 r16 form (W2s LDS) ----
__global__ __launch_bounds__(256) void pull64_xw2(
    const int* __restrict__ rowptr, const int* __restrict__ deg,
    const int* __restrict__ col, const __half* __restrict__ h1,
    const float* __restrict__ out_norm, const float* __restrict__ in_norm,
    const float* __restrict__ b1, const float* __restrict__ W2,
    __half* __restrict__ h2, int n) {
  __shared__ float W2s[64 * 32];   // 8 KB
  __shared__ float xrow[32][64];   // 8 KB
  int t = threadIdx.x;
#pragma unroll
  for (int i = 0; i < 8; i++) W2s[i * 256 + t] = W2[i * 256 + t];

  int w = t >> 6, l = t & 63, g = l >> 3, fq = l & 7;
  int r = w * 8 + g;                 // row in block (0..31)
  int node = blockIdx.x * 32 + r;

  if (node < n) {
    int beg = rowptr[node];
    int dg = deg[node];
    float a0[8] = {0, 0, 0, 0, 0, 0, 0, 0};
    float a1[8] = {0, 0, 0, 0, 0, 0, 0, 0};
    int i = 0;
    for (; i + 4 <= dg; i += 4) {
      int s0 = col[beg + i];
      int s1 = col[beg + i + 1];
      int s2 = col[beg + i + 2];
      int s3 = col[beg + i + 3];
      uint4 v0 = ((const uint4*)h1)[(size_t)s0 * 8 + fq];
      uint4 v1 = ((const uint4*)h1)[(size_t)s1 * 8 + fq];
      uint4 v2 = ((const uint4*)h1)[(size_t)s2 * 8 + fq];
      uint4 v3 = ((const uint4*)h1)[(size_t)s3 * 8 + fq];
      add8h(a0, v0);
      add8h(a1, v1);
      add8h(a0, v2);
      add8h(a1, v3);
    }
    for (; i < dg; i++) {
      int s = col[beg + i];
      uint4 v = ((const uint4*)h1)[(size_t)s * 8 + fq];
      add8h(a0, v);
    }
    float innv = in_norm[node];
    float onnv = out_norm[node];
    float4 ba = ((const float4*)b1)[fq * 2];
    float4 bb = ((const float4*)b1)[fq * 2 + 1];
    float4 o0, o1;
    o0.x = fmaxf((a0[0] + a1[0]) * innv + ba.x, 0.0f) * onnv;
    o0.y = fmaxf((a0[1] + a1[1]) * innv + ba.y, 0.0f) * onnv;
    o0.z = fmaxf((a0[2] + a1[2]) * innv + ba.z, 0.0f) * onnv;
    o0.w = fmaxf((a0[3] + a1[3]) * innv + ba.w, 0.0f) * onnv;
    o1.x = fmaxf((a0[4] + a1[4]) * innv + bb.x, 0.0f) * onnv;
    o1.y = fmaxf((a0[5] + a1[5]) * innv + bb.y, 0.0f) * onnv;
    o1.z = fmaxf((a0[6] + a1[6]) * innv + bb.z, 0.0f) * onnv;
    o1.w = fmaxf((a0[7] + a1[7]) * innv + bb.w, 0.0f) * onnv;
    *(float4*)&xrow[r][fq * 8] = o0;
    *(float4*)&xrow[r][fq * 8 + 4] = o1;
  }
  __syncthreads();
  // phase 2: h2[node][c] = xrow @ W2; 256 threads x 4 rows each (r16 form)
  int c = t & 31, nq = t >> 5;
#pragma unroll
  for (int p = 0; p < 4; p++) {
    int rr = p * 8 + nq;
    int nd = blockIdx.x * 32 + rr;
    if (nd < n) {
      float dot = 0.f;
#pragma unroll 16
      for (int k = 0; k < 64; k++) dot += xrow[rr][k] * W2s[k * 32 + c];
      h2[(size_t)nd * 32 + c] = __float2half(dot);
    }
  }
}

// ---- pull 32 feats + epilogue: wave = 16 nodes x 4 lanes; ILP-4 ----
__global__ __launch_bounds__(256) void gcn_pull32(const int* __restrict__ rowptr,
                                                  const int* __restrict__ deg,
                                                  const int* __restrict__ col,
                                                  const __half* __restrict__ h,
                                                  const float* __restrict__ in_norm,
                                                  const float* __restrict__ b2,
                                                  float* __restrict__ out, int n) {
  int t = threadIdx.x;
  int w = t >> 6, l = t & 63, g = l >> 2, fq = l & 3;
  int node = blockIdx.x * 64 + w * 16 + g;
  if (node >= n) return;
  int beg = rowptr[node];
  int dg = deg[node];
  float a0[8] = {0, 0, 0, 0, 0, 0, 0, 0};
  float a1[8] = {0, 0, 0, 0, 0, 0, 0, 0};
  int i = 0;
  for (; i + 4 <= dg; i += 4) {
    int s0 = col[beg + i];
    int s1 = col[beg + i + 1];
    int s2 = col[beg + i + 2];
    int s3 = col[beg + i + 3];
    uint4 v0 = ((const uint4*)h)[(size_t)s0 * 4 + fq];
    uint4 v1 = ((const uint4*)h)[(size_t)s1 * 4 + fq];
    uint4 v2 = ((const uint4*)h)[(size_t)s2 * 4 + fq];
    uint4 v3 = ((const uint4*)h)[(size_t)s3 * 4 + fq];
    add8h(a0, v0);
    add8h(a1, v1);
    add8h(a0, v2);
    add8h(a1, v3);
  }
  for (; i < dg; i++) {
    int s = col[beg + i];
    uint4 v = ((const uint4*)h)[(size_t)s * 4 + fq];
    add8h(a0, v);
  }
  float innv = in_norm[node];
  float4 b2a = ((const float4*)b2)[fq * 2];
  float4 b2b = ((const float4*)b2)[fq * 2 + 1];
  float4 o0, o1;
  o0.x = (a0[0] + a1[0]) * innv + b2a.x;
  o0.y = (a0[1] + a1[1]) * innv + b2a.y;
  o0.z = (a0[2] + a1[2]) * innv + b2a.z;
  o0.w = (a0[3] + a1[3]) * innv + b2a.w;
  o1.x = (a0[4] + a1[4]) * innv + b2b.x;
  o1.y = (a0[5] + a1[5]) * innv + b2b.y;
  o1.z = (a0[6] + a1[6]) * innv + b2b.z;
  o1.w = (a0[7] + a1[7]) * innv + b2b.w;
  ((float4*)out)[(size_t)node * 8 + fq * 2] = o0;
  ((float4*)out)[(size_t)node * 8 + fq * 2 + 1] = o1;
}

extern "C" void kernel_launch(void* const* d_in, const int* in_sizes, int n_in,
                              void* d_out, int out_size, void* d_ws, size_t ws_size,
                              hipStream_t stream) {
  const float* x   = (const float*)d_in[0];
  const int*   src = (const int*)d_in[1];
  const int*   dst = (const int*)d_in[2];
  const float* W1  = (const float*)d_in[3];
  const float* b1  = (const float*)d_in[4];
  const float* W2  = (const float*)d_in[5];
  const float* b2  = (const float*)d_in[6];
  float* out = (float*)d_out;

  const int N = in_sizes[0] / 64;   // 100000
  const int E = in_sizes[1];        // 1600000

  int* deg        = (int*)d_ws;                // N
  int* rowptr     = deg + N;                   // N
  float* in_norm  = (float*)(rowptr + N);      // N
  float* out_norm = in_norm + N;               // N
  int* gcur       = (int*)(out_norm + N);      // 1024
  int* col        = gcur + 1024;               // E (compact)
  __half* h1 = (__half*)(col + E);             // 64N halves
  __half* h2 = h1 + (size_t)64 * N;            // 32N halves
  int* binbuf_d = (int*)h2;                    // 391*CAP ints (aliases h2+, dead later)
  unsigned char* binbuf_s =
      (unsigned char*)(binbuf_d + (size_t)NBINS * CAP);  // 391*CAP bytes

  hipMemsetAsync(gcur, 0, 1024 * sizeof(int), stream);

  const int NKB = (E + 1024 * KB_EPT - 1) / (1024 * KB_EPT);  // 196
  const int GX = (N + 15) / 16;                               // 6250
  kB_scatter<<<NKB, 1024, 0, stream>>>(src, dst, gcur, binbuf_d, binbuf_s, E);
  xw1<<<GX, 256, 0, stream>>>(x, W1, h1, N);
  kC_build<<<2 * NBINS, 256, 0, stream>>>(gcur, binbuf_d, binbuf_s, col, rowptr,
                                          deg, in_norm, out_norm, h1, N);
  pull64_xw2<<<(N + 31) / 32, 256, 0, stream>>>(rowptr, deg, col, h1, out_norm,
                                                in_norm, b1, W2, h2, N);
  gcn_pull32<<<(N + 63) / 64, 256, 0, stream>>>(rowptr, deg, col, h2, in_norm,
                                                b2, out, N);
}

// Round 13
// 208.391 us; speedup vs baseline: 1.2089x; 1.0404x over previous
//
#include <hip/hip_runtime.h>
#include <hip/hip_fp16.h>

// GCN 2-layer GraphConv (norm='both'), fp32 in/out, fp16 intermediates.
// Round 19: re-fuse kB + xw1 at 1024 threads/block.
//   r10-12 fusion failed at 256t (52KB LDS -> 3 blk/CU = 12 waves, 37%).
//   At 1024t: 2 blk/CU x 52KB = 104KB < 160KB and 2 x 16 = 32 waves = FULL
//   occupancy. kB body byte-identical to r18 (idx replaces blockIdx);
//   xw1 = proven r16 shape scaled to 64 rows/block (acc[4], bcast float4).
//   kC / pull64 (ILP-4) / pull32 byte-identical to r18.
//
// ws: int deg[N] | rowptr[N] | f32 in_norm[N] | out_norm[N] | int gcur[1024] |
//     int col[E] | f16 h1[64N] | f16 h2[32N]
//     binbuf_d[391*CAP ints] aliases h2+ (dead before pull64 writes h2);
//     binbuf_s[391*CAP bytes] follows.

#define BIN_SH 8
#define NBINS 391             // ceil(100000/256)
#define SRC_OFF 512
#define CAP 5120              // mean 4096 + 16 sigma
#define KB_EPT 8              // 8192 edges per 1024-thread kB block

// ---- kBx: kB LDS-staged multisplit (isKB) || xw1 64 rows/block (else) ----
__global__ __launch_bounds__(1024) void kBx(
    const int* __restrict__ src, const int* __restrict__ dst,
    int* __restrict__ gcur, int* __restrict__ binbuf_d,
    unsigned char* __restrict__ binbuf_s,
    const float* __restrict__ x, const float* __restrict__ W,
    __half* __restrict__ h1, int E, int n, int NKB, int GX) {
  __shared__ __align__(16) char smem[53248];
  int bid = blockIdx.x;
  int Mn = (NKB < GX) ? NKB : GX;
  bool isKB;
  int idx;
  if (bid < 2 * Mn) { isKB = !(bid & 1); idx = bid >> 1; }
  else               { isKB = (NKB > GX); idx = bid - 2 * Mn + Mn; }

  int t = threadIdx.x;
  if (isKB) {
    int* stage_d = (int*)smem;                         // 8192 ints (32 KB)
    unsigned char* stage_s = (unsigned char*)(smem + 32768);  // 8192 B
    int* cnt_d  = (int*)(smem + 40960);                // 512
    int* cnt_s  = (int*)(smem + 43008);                // 512
    int* scan_d = (int*)(smem + 45056);                // 512
    int* scan_s = (int*)(smem + 47104);                // 512
    int* base_d = (int*)(smem + 49152);                // 512
    int* base_s = (int*)(smem + 51200);                // 512

    if (t < 512) { cnt_d[t] = 0; cnt_s[t] = 0; }
    __syncthreads();
    int base = idx * (1024 * KB_EPT);
    // pass 1: count
#pragma unroll
    for (int i = 0; i < KB_EPT; i++) {
      int e = base + i * 1024 + t;
      if (e < E) {
        atomicAdd(&cnt_d[dst[e] >> BIN_SH], 1);
        atomicAdd(&cnt_s[src[e] >> BIN_SH], 1);
      }
    }
    __syncthreads();
    // pass 2: two independent 512-entry scans via masked HS over 1024 threads
    {
      int* tmp = stage_d;
      int v = (t < 512) ? cnt_d[t] : cnt_s[t - 512];
      tmp[t] = v;
      __syncthreads();
#pragma unroll
      for (int off = 1; off < 512; off <<= 1) {
        int val = ((t & 511) >= off) ? tmp[t - off] : 0;
        __syncthreads();
        tmp[t] += val;
        __syncthreads();
      }
      int ex = tmp[t] - v;
      if (t < 512) scan_d[t] = ex; else scan_s[t - 512] = ex;
      __syncthreads();
    }
    // pass 2b: reserve global segments; then reset cnt as place cursors
    if (t < 512) {
      int c = cnt_d[t];
      base_d[t] = c ? atomicAdd(&gcur[t], c) : 0;
    } else {
      int i = t - 512;
      int cs = cnt_s[i];
      base_s[i] = cs ? atomicAdd(&gcur[SRC_OFF + i], cs) : 0;
    }
    __syncthreads();
    if (t < 512) { cnt_d[t] = 0; cnt_s[t] = 0; }
    __syncthreads();
    // pass 3: scatter into LDS staging (re-read src/dst, L2-hot)
#pragma unroll
    for (int i = 0; i < KB_EPT; i++) {
      int e = base + i * 1024 + t;
      if (e < E) {
        int d = dst[e], s = src[e];
        int bd = d >> BIN_SH;
        int rd = atomicAdd(&cnt_d[bd], 1);
        stage_d[scan_d[bd] + rd] = ((d & 255) << 17) | s;
        int bs = s >> BIN_SH;
        int rs = atomicAdd(&cnt_s[bs], 1);
        stage_s[scan_s[bs] + rs] = (unsigned char)(s & 255);
      }
    }
    __syncthreads();
    // pass 4: coalesced per-bin segment copy to global (16 waves)
    int wv = t >> 6, ln = t & 63;
    for (int b = wv; b < NBINS; b += 16) {
      int sd = scan_d[b], cd = scan_d[b + 1] - sd;
      int gd = b * CAP + base_d[b];
      for (int j = ln; j < cd; j += 64) binbuf_d[gd + j] = stage_d[sd + j];
      int ss = scan_s[b], cs = scan_s[b + 1] - ss;
      int gs = b * CAP + base_s[b];
      for (int j = ln; j < cs; j += 64) binbuf_s[gs + j] = stage_s[ss + j];
    }
    return;
  }
  // ---- xw1: 64 rows/block, 1024 threads, broadcast-float4 inner loop ----
  float* Ws = (float*)smem;        // 16 KB
  float* xs = Ws + 64 * 64;        // 16 KB (64 rows x 64 cols)
#pragma unroll
  for (int i = 0; i < 4; i++) Ws[i * 1024 + t] = W[i * 1024 + t];
  int row0 = idx * 64;
  {
    int r = t >> 4, k4 = t & 15;   // 64 rows x 16 float4
    int row = row0 + r;
    float4 v = make_float4(0.f, 0.f, 0.f, 0.f);
    if (row < n) v = ((const float4*)x)[(size_t)row * 16 + k4];
    ((float4*)xs)[t] = v;
  }
  __syncthreads();
  int c = t & 63, rq = t >> 6;     // rq in [0,16): wave id; rows rq + rr*16
  float acc[4] = {0.f, 0.f, 0.f, 0.f};
#pragma unroll 4
  for (int kq = 0; kq < 16; kq++) {
    float w0 = Ws[(4 * kq + 0) * 64 + c];
    float w1 = Ws[(4 * kq + 1) * 64 + c];
    float w2 = Ws[(4 * kq + 2) * 64 + c];
    float w3 = Ws[(4 * kq + 3) * 64 + c];
#pragma unroll
    for (int rr = 0; rr < 4; rr++) {
      const float4 xv = *(const float4*)&xs[(rq + rr * 16) * 64 + kq * 4];
      acc[rr] += xv.x * w0 + xv.y * w1 + xv.z * w2 + xv.w * w3;
    }
  }
#pragma unroll
  for (int rr = 0; rr < 4; rr++) {
    int row = row0 + rq + rr * 16;
    if (row < n) h1[(size_t)row * 64 + c] = __float2half(acc[rr]);
  }
}

// ---- kC: [0,NBINS) dst CSR build; [NBINS,2*NBINS) src count -> out_norm,
//          then prescale h1 rows by out_norm (in place, coalesced) ----
__global__ __launch_bounds__(256) void kC_build(
    const int* __restrict__ gcur, const int* __restrict__ binbuf_d,
    const unsigned char* __restrict__ binbuf_s,
    int* __restrict__ col, int* __restrict__ rowptr, int* __restrict__ deg,
    float* __restrict__ in_norm, float* __restrict__ out_norm,
    __half* __restrict__ h1, int n) {
  __shared__ int lcnt[256];
  __shared__ int lptr[256];
  __shared__ int red[256];
  int b = blockIdx.x;
  int t = threadIdx.x;
  if (b >= NBINS) {
    // src-bin byte count -> out_norm, then scale h1 rows of this bin
    int sb = b - NBINS;
    int cnt = gcur[SRC_OFF + sb];
    const unsigned int* p4 =
        (const unsigned int*)(binbuf_s + (size_t)sb * CAP);
    lcnt[t] = 0;
    __syncthreads();
    int cw = (cnt + 3) >> 2;
    for (int i = t; i < cw; i += 256) {
      unsigned int v = p4[i];
      int rem = cnt - i * 4;
      atomicAdd(&lcnt[v & 255], 1);
      if (rem > 1) atomicAdd(&lcnt[(v >> 8) & 255], 1);
      if (rem > 2) atomicAdd(&lcnt[(v >> 16) & 255], 1);
      if (rem > 3) atomicAdd(&lcnt[v >> 24], 1);
    }
    __syncthreads();
    int node0 = sb << BIN_SH;
    int node = node0 + t;
    float o = rsqrtf(fmaxf((float)lcnt[t], 1.0f));
    if (node < n) out_norm[node] = o;
    float* onn = (float*)lptr;
    onn[t] = o;
    __syncthreads();
    uint4* h1q = (uint4*)h1 + (size_t)node0 * 8;
#pragma unroll
    for (int i = 0; i < 8; i++) {
      int idx = i * 256 + t;
      int r = idx >> 3;
      if (node0 + r < n) {
        float sc = onn[r];
        uint4 v = h1q[idx];
        __half2* hp = (__half2*)&v;
#pragma unroll
        for (int q = 0; q < 4; q++) {
          float2 f = __half22float2(hp[q]);
          f.x *= sc; f.y *= sc;
          hp[q] = __float22half2_rn(f);
        }
        h1q[idx] = v;
      }
    }
    return;
  }
  // compact col base = sum of dst-bin counts before b
  int part = 0;
  if (t < b) part = gcur[t];
  if (t + 256 < b) part += gcur[t + 256];
  red[t] = part;
  __syncthreads();
#pragma unroll
  for (int off = 128; off > 0; off >>= 1) {
    if (t < off) red[t] += red[t + off];
    __syncthreads();
  }
  int ebase = red[0];
  int cnt = gcur[b];
  const int* items = binbuf_d + (size_t)b * CAP;
  lcnt[t] = 0;
  __syncthreads();
  for (int i = t; i < cnt; i += 256) atomicAdd(&lcnt[items[i] >> 17], 1);
  __syncthreads();
  int cv = lcnt[t];
  lptr[t] = cv;
  __syncthreads();
#pragma unroll
  for (int off = 1; off < 256; off <<= 1) {
    int val = (t >= off) ? lptr[t - off] : 0;
    __syncthreads();
    lptr[t] += val;
    __syncthreads();
  }
  int ex = lptr[t] - cv;
  int node = (b << BIN_SH) + t;
  if (node < n) {
    rowptr[node] = ebase + ex;
    deg[node] = cv;
    in_norm[node] = rsqrtf(fmaxf((float)cv, 1.0f));
  }
  __syncthreads();
  lptr[t] = ex;
  __syncthreads();
  for (int i = t; i < cnt; i += 256) {
    int v = items[i];
    int r = atomicAdd(&lptr[v >> 17], 1);
    col[ebase + r] = v & 0x1FFFF;   // block-local region -> L2 merges
  }
}

__device__ inline void add8h(float* a, uint4 r) {
  const __half2* hp = reinterpret_cast<const __half2*>(&r);
#pragma unroll
  for (int i = 0; i < 4; i++) {
    float2 f = __half22float2(hp[i]);
    a[2 * i] += f.x;
    a[2 * i + 1] += f.y;
  }
}

// ---- pull64 + fused xw2: wave = 8 nodes x 8 lanes; ILP-4 gather;
//      phase2 W2s LDS (r18 proven) ----
__global__ __launch_bounds__(256) void pull64_xw2(
    const int* __restrict__ rowptr, const int* __restrict__ deg,
    const int* __restrict__ col, const __half* __restrict__ h1,
    const float* __restrict__ out_norm, const float* __restrict__ in_norm,
    const float* __restrict__ b1, const float* __restrict__ W2,
    __half* __restrict__ h2, int n) {
  __shared__ float W2s[64 * 32];   // 8 KB
  __shared__ float xrow[32][64];   // 8 KB
  int t = threadIdx.x;
#pragma unroll
  for (int i = 0; i < 8; i++) W2s[i * 256 + t] = W2[i * 256 + t];

  int w = t >> 6, l = t & 63, g = l >> 3, fq = l & 7;
  int r = w * 8 + g;                 // row in block (0..31)
  int node = blockIdx.x * 32 + r;

  if (node < n) {
    int beg = rowptr[node];
    int dg = deg[node];
    float a0[8] = {0, 0, 0, 0, 0, 0, 0, 0};
    float a1[8] = {0, 0, 0, 0, 0, 0, 0, 0};
    int i = 0;
    for (; i + 4 <= dg; i += 4) {
      int s0 = col[beg + i];
      int s1 = col[beg + i + 1];
      int s2 = col[beg + i + 2];
      int s3 = col[beg + i + 3];
      uint4 v0 = ((const uint4*)h1)[(size_t)s0 * 8 + fq];
      uint4 v1 = ((const uint4*)h1)[(size_t)s1 * 8 + fq];
      uint4 v2 = ((const uint4*)h1)[(size_t)s2 * 8 + fq];
      uint4 v3 = ((const uint4*)h1)[(size_t)s3 * 8 + fq];
      add8h(a0, v0);
      add8h(a1, v1);
      add8h(a0, v2);
      add8h(a1, v3);
    }
    for (; i < dg; i++) {
      int s = col[beg + i];
      uint4 v = ((const uint4*)h1)[(size_t)s * 8 + fq];
      add8h(a0, v);
    }
    float innv = in_norm[node];
    float onnv = out_norm[node];
    float4 ba = ((const float4*)b1)[fq * 2];
    float4 bb = ((const float4*)b1)[fq * 2 + 1];
    float4 o0, o1;
    o0.x = fmaxf((a0[0] + a1[0]) * innv + ba.x, 0.0f) * onnv;
    o0.y = fmaxf((a0[1] + a1[1]) * innv + ba.y, 0.0f) * onnv;
    o0.z = fmaxf((a0[2] + a1[2]) * innv + ba.z, 0.0f) * onnv;
    o0.w = fmaxf((a0[3] + a1[3]) * innv + ba.w, 0.0f) * onnv;
    o1.x = fmaxf((a0[4] + a1[4]) * innv + bb.x, 0.0f) * onnv;
    o1.y = fmaxf((a0[5] + a1[5]) * innv + bb.y, 0.0f) * onnv;
    o1.z = fmaxf((a0[6] + a1[6]) * innv + bb.z, 0.0f) * onnv;
    o1.w = fmaxf((a0[7] + a1[7]) * innv + bb.w, 0.0f) * onnv;
    *(float4*)&xrow[r][fq * 8] = o0;
    *(float4*)&xrow[r][fq * 8 + 4] = o1;
  }
  __syncthreads();
  // phase 2: h2[node][c] = xrow @ W2; 256 threads x 4 rows each
  int c = t & 31, nq = t >> 5;
#pragma unroll
  for (int p = 0; p < 4; p++) {
    int rr = p * 8 + nq;
    int nd = blockIdx.x * 32 + rr;
    if (nd < n) {
      float dot = 0.f;
#pragma unroll 16
      for (int k = 0; k < 64; k++) dot += xrow[rr][k] * W2s[k * 32 + c];
      h2[(size_t)nd * 32 + c] = __float2half(dot);
    }
  }
}

// ---- pull 32 feats + epilogue: wave = 16 nodes x 4 lanes; ILP-4 ----
__global__ __launch_bounds__(256) void gcn_pull32(const int* __restrict__ rowptr,
                                                  const int* __restrict__ deg,
                                                  const int* __restrict__ col,
                                                  const __half* __restrict__ h,
                                                  const float* __restrict__ in_norm,
                                                  const float* __restrict__ b2,
                                                  float* __restrict__ out, int n) {
  int t = threadIdx.x;
  int w = t >> 6, l = t & 63, g = l >> 2, fq = l & 3;
  int node = blockIdx.x * 64 + w * 16 + g;
  if (node >= n) return;
  int beg = rowptr[node];
  int dg = deg[node];
  float a0[8] = {0, 0, 0, 0, 0, 0, 0, 0};
  float a1[8] = {0, 0, 0, 0, 0, 0, 0, 0};
  int i = 0;
  for (; i + 4 <= dg; i += 4) {
    int s0 = col[beg + i];
    int s1 = col[beg + i + 1];
    int s2 = col[beg + i + 2];
    int s3 = col[beg + i + 3];
    uint4 v0 = ((const uint4*)h)[(size_t)s0 * 4 + fq];
    uint4 v1 = ((const uint4*)h)[(size_t)s1 * 4 + fq];
    uint4 v2 = ((const uint4*)h)[(size_t)s2 * 4 + fq];
    uint4 v3 = ((const uint4*)h)[(size_t)s3 * 4 + fq];
    add8h(a0, v0);
    add8h(a1, v1);
    add8h(a0, v2);
    add8h(a1, v3);
  }
  for (; i < dg; i++) {
    int s = col[beg + i];
    uint4 v = ((const uint4*)h)[(size_t)s * 4 + fq];
    add8h(a0, v);
  }
  float innv = in_norm[node];
  float4 b2a = ((const float4*)b2)[fq * 2];
  float4 b2b = ((const float4*)b2)[fq * 2 + 1];
  float4 o0, o1;
  o0.x = (a0[0] + a1[0]) * innv + b2a.x;
  o0.y = (a0[1] + a1[1]) * innv + b2a.y;
  o0.z = (a0[2] + a1[2]) * innv + b2a.z;
  o0.w = (a0[3] + a1[3]) * innv + b2a.w;
  o1.x = (a0[4] + a1[4]) * innv + b2b.x;
  o1.y = (a0[5] + a1[5]) * innv + b2b.y;
  o1.z = (a0[6] + a1[6]) * innv + b2b.z;
  o1.w = (a0[7] + a1[7]) * innv + b2b.w;
  ((float4*)out)[(size_t)node * 8 + fq * 2] = o0;
  ((float4*)out)[(size_t)node * 8 + fq * 2 + 1] = o1;
}

extern "C" void kernel_launch(void* const* d_in, const int* in_sizes, int n_in,
                              void* d_out, int out_size, void* d_ws, size_t ws_size,
                              hipStream_t stream) {
  const float* x   = (const float*)d_in[0];
  const int*   src = (const int*)d_in[1];
  const int*   dst = (const int*)d_in[2];
  const float* W1  = (const float*)d_in[3];
  const float* b1  = (const float*)d_in[4];
  const float* W2  = (const float*)d_in[5];
  const float* b2  = (const float*)d_in[6];
  float* out = (float*)d_out;

  const int N = in_sizes[0] / 64;   // 100000
  const int E = in_sizes[1];        // 1600000

  int* deg        = (int*)d_ws;                // N
  int* rowptr     = deg + N;                   // N
  float* in_norm  = (float*)(rowptr + N);      // N
  float* out_norm = in_norm + N;               // N
  int* gcur       = (int*)(out_norm + N);      // 1024
  int* col        = gcur + 1024;               // E (compact)
  __half* h1 = (__half*)(col + E);             // 64N halves
  __half* h2 = h1 + (size_t)64 * N;            // 32N halves
  int* binbuf_d = (int*)h2;                    // 391*CAP ints (aliases h2+, dead later)
  unsigned char* binbuf_s =
      (unsigned char*)(binbuf_d + (size_t)NBINS * CAP);  // 391*CAP bytes

  hipMemsetAsync(gcur, 0, 1024 * sizeof(int), stream);

  const int NKB = (E + 1024 * KB_EPT - 1) / (1024 * KB_EPT);  // 196
  const int GX = (N + 63) / 64;                               // 1563
  kBx<<<NKB + GX, 1024, 0, stream>>>(src, dst, gcur, binbuf_d, binbuf_s,
                                     x, W1, h1, E, N, NKB, GX);
  kC_build<<<2 * NBINS, 256, 0, stream>>>(gcur, binbuf_d, binbuf_s, col, rowptr,
                                          deg, in_norm, out_norm, h1, N);
  pull64_xw2<<<(N + 31) / 32, 256, 0, stream>>>(rowptr, deg, col, h1, out_norm,
                                                in_norm, b1, W2, h2, N);
  gcn_pull32<<<(N + 63) / 64, 256, 0, stream>>>(rowptr, deg, col, h2, in_norm,
                                                b2, out, N);
}

// Round 14
// 204.246 us; speedup vs baseline: 1.2335x; 1.0203x over previous
//
#include <hip/hip_runtime.h>
#include <hip/hip_fp16.h>

// GCN 2-layer GraphConv (norm='both'), fp32 in/out, fp16 intermediates.
// Round 20: kC_build -> 1024 threads (heavy strided loops get 4x fewer
//   iters/thread: count 16->4, place 16->4, prescale 8->2, byte-count 4->1;
//   scans stay on first 256 threads; gcur prefix = 1024-wide tree).
//   Same lever that fixed kB_scatter in r14 (66->~25us).
//   kBx / pull64 (ILP-4) / pull32 (ILP-4) byte-identical to r19.
//
// ws: int deg[N] | rowptr[N] | f32 in_norm[N] | out_norm[N] | int gcur[1024] |
//     int col[E] | f16 h1[64N] | f16 h2[32N]
//     binbuf_d[391*CAP ints] aliases h2+ (dead before pull64 writes h2);
//     binbuf_s[391*CAP bytes] follows.

#define BIN_SH 8
#define NBINS 391             // ceil(100000/256)
#define SRC_OFF 512
#define CAP 5120              // mean 4096 + 16 sigma
#define KB_EPT 8              // 8192 edges per 1024-thread kB block

// ---- kBx: kB LDS-staged multisplit (isKB) || xw1 64 rows/block (else) ----
__global__ __launch_bounds__(1024) void kBx(
    const int* __restrict__ src, const int* __restrict__ dst,
    int* __restrict__ gcur, int* __restrict__ binbuf_d,
    unsigned char* __restrict__ binbuf_s,
    const float* __restrict__ x, const float* __restrict__ W,
    __half* __restrict__ h1, int E, int n, int NKB, int GX) {
  __shared__ __align__(16) char smem[53248];
  int bid = blockIdx.x;
  int Mn = (NKB < GX) ? NKB : GX;
  bool isKB;
  int idx;
  if (bid < 2 * Mn) { isKB = !(bid & 1); idx = bid >> 1; }
  else               { isKB = (NKB > GX); idx = bid - 2 * Mn + Mn; }

  int t = threadIdx.x;
  if (isKB) {
    int* stage_d = (int*)smem;                         // 8192 ints (32 KB)
    unsigned char* stage_s = (unsigned char*)(smem + 32768);  // 8192 B
    int* cnt_d  = (int*)(smem + 40960);                // 512
    int* cnt_s  = (int*)(smem + 43008);                // 512
    int* scan_d = (int*)(smem + 45056);                // 512
    int* scan_s = (int*)(smem + 47104);                // 512
    int* base_d = (int*)(smem + 49152);                // 512
    int* base_s = (int*)(smem + 51200);                // 512

    if (t < 512) { cnt_d[t] = 0; cnt_s[t] = 0; }
    __syncthreads();
    int base = idx * (1024 * KB_EPT);
    // pass 1: count
#pragma unroll
    for (int i = 0; i < KB_EPT; i++) {
      int e = base + i * 1024 + t;
      if (e < E) {
        atomicAdd(&cnt_d[dst[e] >> BIN_SH], 1);
        atomicAdd(&cnt_s[src[e] >> BIN_SH], 1);
      }
    }
    __syncthreads();
    // pass 2: two independent 512-entry scans via masked HS over 1024 threads
    {
      int* tmp = stage_d;
      int v = (t < 512) ? cnt_d[t] : cnt_s[t - 512];
      tmp[t] = v;
      __syncthreads();
#pragma unroll
      for (int off = 1; off < 512; off <<= 1) {
        int val = ((t & 511) >= off) ? tmp[t - off] : 0;
        __syncthreads();
        tmp[t] += val;
        __syncthreads();
      }
      int ex = tmp[t] - v;
      if (t < 512) scan_d[t] = ex; else scan_s[t - 512] = ex;
      __syncthreads();
    }
    // pass 2b: reserve global segments; then reset cnt as place cursors
    if (t < 512) {
      int c = cnt_d[t];
      base_d[t] = c ? atomicAdd(&gcur[t], c) : 0;
    } else {
      int i = t - 512;
      int cs = cnt_s[i];
      base_s[i] = cs ? atomicAdd(&gcur[SRC_OFF + i], cs) : 0;
    }
    __syncthreads();
    if (t < 512) { cnt_d[t] = 0; cnt_s[t] = 0; }
    __syncthreads();
    // pass 3: scatter into LDS staging (re-read src/dst, L2-hot)
#pragma unroll
    for (int i = 0; i < KB_EPT; i++) {
      int e = base + i * 1024 + t;
      if (e < E) {
        int d = dst[e], s = src[e];
        int bd = d >> BIN_SH;
        int rd = atomicAdd(&cnt_d[bd], 1);
        stage_d[scan_d[bd] + rd] = ((d & 255) << 17) | s;
        int bs = s >> BIN_SH;
        int rs = atomicAdd(&cnt_s[bs], 1);
        stage_s[scan_s[bs] + rs] = (unsigned char)(s & 255);
      }
    }
    __syncthreads();
    // pass 4: coalesced per-bin segment copy to global (16 waves)
    int wv = t >> 6, ln = t & 63;
    for (int b = wv; b < NBINS; b += 16) {
      int sd = scan_d[b], cd = scan_d[b + 1] - sd;
      int gd = b * CAP + base_d[b];
      for (int j = ln; j < cd; j += 64) binbuf_d[gd + j] = stage_d[sd + j];
      int ss = scan_s[b], cs = scan_s[b + 1] - ss;
      int gs = b * CAP + base_s[b];
      for (int j = ln; j < cs; j += 64) binbuf_s[gs + j] = stage_s[ss + j];
    }
    return;
  }
  // ---- xw1: 64 rows/block, 1024 threads, broadcast-float4 inner loop ----
  float* Ws = (float*)smem;        // 16 KB
  float* xs = Ws + 64 * 64;        // 16 KB (64 rows x 64 cols)
#pragma unroll
  for (int i = 0; i < 4; i++) Ws[i * 1024 + t] = W[i * 1024 + t];
  int row0 = idx * 64;
  {
    int r = t >> 4, k4 = t & 15;   // 64 rows x 16 float4
    int row = row0 + r;
    float4 v = make_float4(0.f, 0.f, 0.f, 0.f);
    if (row < n) v = ((const float4*)x)[(size_t)row * 16 + k4];
    ((float4*)xs)[t] = v;
  }
  __syncthreads();
  int c = t & 63, rq = t >> 6;     // rq in [0,16): wave id; rows rq + rr*16
  float acc[4] = {0.f, 0.f, 0.f, 0.f};
#pragma unroll 4
  for (int kq = 0; kq < 16; kq++) {
    float w0 = Ws[(4 * kq + 0) * 64 + c];
    float w1 = Ws[(4 * kq + 1) * 64 + c];
    float w2 = Ws[(4 * kq + 2) * 64 + c];
    float w3 = Ws[(4 * kq + 3) * 64 + c];
#pragma unroll
    for (int rr = 0; rr < 4; rr++) {
      const float4 xv = *(const float4*)&xs[(rq + rr * 16) * 64 + kq * 4];
      acc[rr] += xv.x * w0 + xv.y * w1 + xv.z * w2 + xv.w * w3;
    }
  }
#pragma unroll
  for (int rr = 0; rr < 4; rr++) {
    int row = row0 + rq + rr * 16;
    if (row < n) h1[(size_t)row * 64 + c] = __float2half(acc[rr]);
  }
}

// ---- kC: 1024 threads. [0,NBINS) dst CSR build; [NBINS,2*NBINS) src count
//      -> out_norm + h1 prescale ----
__global__ __launch_bounds__(1024) void kC_build(
    const int* __restrict__ gcur, const int* __restrict__ binbuf_d,
    const unsigned char* __restrict__ binbuf_s,
    int* __restrict__ col, int* __restrict__ rowptr, int* __restrict__ deg,
    float* __restrict__ in_norm, float* __restrict__ out_norm,
    __half* __restrict__ h1, int n) {
  __shared__ int lcnt[256];
  __shared__ int lptr[256];
  __shared__ int red[1024];
  int b = blockIdx.x;
  int t = threadIdx.x;
  if (b >= NBINS) {
    // src-bin byte count -> out_norm, then scale h1 rows of this bin
    int sb = b - NBINS;
    int cnt = gcur[SRC_OFF + sb];
    const unsigned int* p4 =
        (const unsigned int*)(binbuf_s + (size_t)sb * CAP);
    if (t < 256) lcnt[t] = 0;
    __syncthreads();
    int cw = (cnt + 3) >> 2;
    for (int i = t; i < cw; i += 1024) {
      unsigned int v = p4[i];
      int rem = cnt - i * 4;
      atomicAdd(&lcnt[v & 255], 1);
      if (rem > 1) atomicAdd(&lcnt[(v >> 8) & 255], 1);
      if (rem > 2) atomicAdd(&lcnt[(v >> 16) & 255], 1);
      if (rem > 3) atomicAdd(&lcnt[v >> 24], 1);
    }
    __syncthreads();
    int node0 = sb << BIN_SH;
    float* onn = (float*)lptr;
    if (t < 256) {
      float o = rsqrtf(fmaxf((float)lcnt[t], 1.0f));
      if (node0 + t < n) out_norm[node0 + t] = o;
      onn[t] = o;
    }
    __syncthreads();
    uint4* h1q = (uint4*)h1 + (size_t)node0 * 8;
#pragma unroll
    for (int i = 0; i < 2; i++) {
      int idx = i * 1024 + t;           // uint4 index within bin (2048 total)
      int r = idx >> 3;                 // row within bin
      if (node0 + r < n) {
        float sc = onn[r];
        uint4 v = h1q[idx];
        __half2* hp = (__half2*)&v;
#pragma unroll
        for (int q = 0; q < 4; q++) {
          float2 f = __half22float2(hp[q]);
          f.x *= sc; f.y *= sc;
          hp[q] = __float22half2_rn(f);
        }
        h1q[idx] = v;
      }
    }
    return;
  }
  // ---- dst bin: CSR build ----
  int cnt = gcur[b];
  const int* items = binbuf_d + (size_t)b * CAP;
  if (t < 256) lcnt[t] = 0;
  __syncthreads();
  for (int i = t; i < cnt; i += 1024) atomicAdd(&lcnt[items[i] >> 17], 1);
  // compact col base = sum of dst-bin counts before b (1024-wide tree)
  red[t] = (t < b) ? gcur[t] : 0;     // b < 512
  __syncthreads();
#pragma unroll
  for (int off = 512; off > 0; off >>= 1) {
    if (t < off) red[t] += red[t + off];
    __syncthreads();
  }
  int ebase = red[0];
  // scan of 256 lcnt using first 256 threads (HS)
  int cv = 0;
  if (t < 256) { cv = lcnt[t]; lptr[t] = cv; }
  __syncthreads();
#pragma unroll
  for (int off = 1; off < 256; off <<= 1) {
    int val = (t < 256 && t >= off) ? lptr[t - off] : 0;
    __syncthreads();
    if (t < 256) lptr[t] += val;
    __syncthreads();
  }
  if (t < 256) {
    int ex = lptr[t] - cv;
    int node = (b << BIN_SH) + t;
    if (node < n) {
      rowptr[node] = ebase + ex;
      deg[node] = cv;
      in_norm[node] = rsqrtf(fmaxf((float)cv, 1.0f));
    }
    lptr[t] = ex;                     // becomes place cursor after barrier
  }
  __syncthreads();
  for (int i = t; i < cnt; i += 1024) {
    int v = items[i];
    int r = atomicAdd(&lptr[v >> 17], 1);
    col[ebase + r] = v & 0x1FFFF;     // block-local region -> L2 merges
  }
}

__device__ inline void add8h(float* a, uint4 r) {
  const __half2* hp = reinterpret_cast<const __half2*>(&r);
#pragma unroll
  for (int i = 0; i < 4; i++) {
    float2 f = __half22float2(hp[i]);
    a[2 * i] += f.x;
    a[2 * i + 1] += f.y;
  }
}

// ---- pull64 + fused xw2: wave = 8 nodes x 8 lanes; ILP-4 gather;
//      phase2 W2s LDS (r18 proven) ----
__global__ __launch_bounds__(256) void pull64_xw2(
    const int* __restrict__ rowptr, const int* __restrict__ deg,
    const int* __restrict__ col, const __half* __restrict__ h1,
    const float* __restrict__ out_norm, const float* __restrict__ in_norm,
    const float* __restrict__ b1, const float* __restrict__ W2,
    __half* __restrict__ h2, int n) {
  __shared__ float W2s[64 * 32];   // 8 KB
  __shared__ float xrow[32][64];   // 8 KB
  int t = threadIdx.x;
#pragma unroll
  for (int i = 0; i < 8; i++) W2s[i * 256 + t] = W2[i * 256 + t];

  int w = t >> 6, l = t & 63, g = l >> 3, fq = l & 7;
  int r = w * 8 + g;                 // row in block (0..31)
  int node = blockIdx.x * 32 + r;

  if (node < n) {
    int beg = rowptr[node];
    int dg = deg[node];
    float a0[8] = {0, 0, 0, 0, 0, 0, 0, 0};
    float a1[8] = {0, 0, 0, 0, 0, 0, 0, 0};
    int i = 0;
    for (; i + 4 <= dg; i += 4) {
      int s0 = col[beg + i];
      int s1 = col[beg + i + 1];
      int s2 = col[beg + i + 2];
      int s3 = col[beg + i + 3];
      uint4 v0 = ((const uint4*)h1)[(size_t)s0 * 8 + fq];
      uint4 v1 = ((const uint4*)h1)[(size_t)s1 * 8 + fq];
      uint4 v2 = ((const uint4*)h1)[(size_t)s2 * 8 + fq];
      uint4 v3 = ((const uint4*)h1)[(size_t)s3 * 8 + fq];
      add8h(a0, v0);
      add8h(a1, v1);
      add8h(a0, v2);
      add8h(a1, v3);
    }
    for (; i < dg; i++) {
      int s = col[beg + i];
      uint4 v = ((const uint4*)h1)[(size_t)s * 8 + fq];
      add8h(a0, v);
    }
    float innv = in_norm[node];
    float onnv = out_norm[node];
    float4 ba = ((const float4*)b1)[fq * 2];
    float4 bb = ((const float4*)b1)[fq * 2 + 1];
    float4 o0, o1;
    o0.x = fmaxf((a0[0] + a1[0]) * innv + ba.x, 0.0f) * onnv;
    o0.y = fmaxf((a0[1] + a1[1]) * innv + ba.y, 0.0f) * onnv;
    o0.z = fmaxf((a0[2] + a1[2]) * innv + ba.z, 0.0f) * onnv;
    o0.w = fmaxf((a0[3] + a1[3]) * innv + ba.w, 0.0f) * onnv;
    o1.x = fmaxf((a0[4] + a1[4]) * innv + bb.x, 0.0f) * onnv;
    o1.y = fmaxf((a0[5] + a1[5]) * innv + bb.y, 0.0f) * onnv;
    o1.z = fmaxf((a0[6] + a1[6]) * innv + bb.z, 0.0f) * onnv;
    o1.w = fmaxf((a0[7] + a1[7]) * innv + bb.w, 0.0f) * onnv;
    *(float4*)&xrow[r][fq * 8] = o0;
    *(float4*)&xrow[r][fq * 8 + 4] = o1;
  }
  __syncthreads();
  // phase 2: h2[node][c] = xrow @ W2; 256 threads x 4 rows each
  int c = t & 31, nq = t >> 5;
#pragma unroll
  for (int p = 0; p < 4; p++) {
    int rr = p * 8 + nq;
    int nd = blockIdx.x * 32 + rr;
    if (nd < n) {
      float dot = 0.f;
#pragma unroll 16
      for (int k = 0; k < 64; k++) dot += xrow[rr][k] * W2s[k * 32 + c];
      h2[(size_t)nd * 32 + c] = __float2half(dot);
    }
  }
}

// ---- pull 32 feats + epilogue: wave = 16 nodes x 4 lanes; ILP-4 ----
__global__ __launch_bounds__(256) void gcn_pull32(const int* __restrict__ rowptr,
                                                  const int* __restrict__ deg,
                                                  const int* __restrict__ col,
                                                  const __half* __restrict__ h,
                                                  const float* __restrict__ in_norm,
                                                  const float* __restrict__ b2,
                                                  float* __restrict__ out, int n) {
  int t = threadIdx.x;
  int w = t >> 6, l = t & 63, g = l >> 2, fq = l & 3;
  int node = blockIdx.x * 64 + w * 16 + g;
  if (node >= n) return;
  int beg = rowptr[node];
  int dg = deg[node];
  float a0[8] = {0, 0, 0, 0, 0, 0, 0, 0};
  float a1[8] = {0, 0, 0, 0, 0, 0, 0, 0};
  int i = 0;
  for (; i + 4 <= dg; i += 4) {
    int s0 = col[beg + i];
    int s1 = col[beg + i + 1];
    int s2 = col[beg + i + 2];
    int s3 = col[beg + i + 3];
    uint4 v0 = ((const uint4*)h)[(size_t)s0 * 4 + fq];
    uint4 v1 = ((const uint4*)h)[(size_t)s1 * 4 + fq];
    uint4 v2 = ((const uint4*)h)[(size_t)s2 * 4 + fq];
    uint4 v3 = ((const uint4*)h)[(size_t)s3 * 4 + fq];
    add8h(a0, v0);
    add8h(a1, v1);
    add8h(a0, v2);
    add8h(a1, v3);
  }
  for (; i < dg; i++) {
    int s = col[beg + i];
    uint4 v = ((const uint4*)h)[(size_t)s * 4 + fq];
    add8h(a0, v);
  }
  float innv = in_norm[node];
  float4 b2a = ((const float4*)b2)[fq * 2];
  float4 b2b = ((const float4*)b2)[fq * 2 + 1];
  float4 o0, o1;
  o0.x = (a0[0] + a1[0]) * innv + b2a.x;
  o0.y = (a0[1] + a1[1]) * innv + b2a.y;
  o0.z = (a0[2] + a1[2]) * innv + b2a.z;
  o0.w = (a0[3] + a1[3]) * innv + b2a.w;
  o1.x = (a0[4] + a1[4]) * innv + b2b.x;
  o1.y = (a0[5] + a1[5]) * innv + b2b.y;
  o1.z = (a0[6] + a1[6]) * innv + b2b.z;
  o1.w = (a0[7] + a1[7]) * innv + b2b.w;
  ((float4*)out)[(size_t)node * 8 + fq * 2] = o0;
  ((float4*)out)[(size_t)node * 8 + fq * 2 + 1] = o1;
}

extern "C" void kernel_launch(void* const* d_in, const int* in_sizes, int n_in,
                              void* d_out, int out_size, void* d_ws, size_t ws_size,
                              hipStream_t stream) {
  const float* x   = (const float*)d_in[0];
  const int*   src = (const int*)d_in[1];
  const int*   dst = (const int*)d_in[2];
  const float* W1  = (const float*)d_in[3];
  const float* b1  = (const float*)d_in[4];
  const float* W2  = (const float*)d_in[5];
  const float* b2  = (const float*)d_in[6];
  float* out = (float*)d_out;

  const int N = in_sizes[0] / 64;   // 100000
  const int E = in_sizes[1];        // 1600000

  int* deg        = (int*)d_ws;                // N
  int* rowptr     = deg + N;                   // N
  float* in_norm  = (float*)(rowptr + N);      // N
  float* out_norm = in_norm + N;               // N
  int* gcur       = (int*)(out_norm + N);      // 1024
  int* col        = gcur + 1024;               // E (compact)
  __half* h1 = (__half*)(col + E);             // 64N halves
  __half* h2 = h1 + (size_t)64 * N;            // 32N halves
  int* binbuf_d = (int*)h2;                    // 391*CAP ints (aliases h2+, dead later)
  unsigned char* binbuf_s =
      (unsigned char*)(binbuf_d + (size_t)NBINS * CAP);  // 391*CAP bytes

  hipMemsetAsync(gcur, 0, 1024 * sizeof(int), stream);

  const int NKB = (E + 1024 * KB_EPT - 1) / (1024 * KB_EPT);  // 196
  const int GX = (N + 63) / 64;                               // 1563
  kBx<<<NKB + GX, 1024, 0, stream>>>(src, dst, gcur, binbuf_d, binbuf_s,
                                     x, W1, h1, E, N, NKB, GX);
  kC_build<<<2 * NBINS, 1024, 0, stream>>>(gcur, binbuf_d, binbuf_s, col, rowptr,
                                           deg, in_norm, out_norm, h1, N);
  pull64_xw2<<<(N + 31) / 32, 256, 0, stream>>>(rowptr, deg, col, h1, out_norm,
                                                in_norm, b1, W2, h2, N);
  gcn_pull32<<<(N + 63) / 64, 256, 0, stream>>>(rowptr, deg, col, h2, in_norm,
                                                b2, out, N);
}